// Round 1
// 340.913 us; speedup vs baseline: 1.1115x; 1.1115x over previous
//
#include <hip/hip_runtime.h>
#include <hip/hip_bf16.h>
#include <stdint.h>

typedef __bf16 bf16_t;
typedef bf16_t bf16x8 __attribute__((ext_vector_type(8)));
typedef bf16_t bf16x2 __attribute__((ext_vector_type(2)));
typedef float f32x4 __attribute__((ext_vector_type(4)));

#define E_N 65536
#define T_N 262144
#define CAP 16          // bucket capacity per edge (avg occupancy 4)
#define OVF_MAX T_N     // overflow list can hold every triplet -> always correct

__device__ __forceinline__ float silu_f(float v) {
  return v / (1.0f + __expf(-v));
}

// B-row permutation: LDS row r = tj*16+i holds real output column
// 32*(tj>>1) + 2*i + (tj&1), so each lane's acc[2g],acc[2g+1] are 2
// consecutive real columns -> bf16x2 stores everywhere.
__device__ __forceinline__ int permrow(int n) {
  return (n & ~31) | ((n & 1) << 4) | ((n & 30) >> 1);
}

__device__ __forceinline__ uint32_t pack_bf16(float a, float b) {
  union { bf16x2 h; uint32_t u; } u;
  u.h[0] = (bf16_t)a; u.h[1] = (bf16_t)b;
  return u.u;
}

// ---- MFMA tile GEMM on swizzled stride-128 LDS tiles ----
// element (row,k) stored at row*128 + (((k>>3) ^ (row&15))<<3) + (k&7)
template<int KI, int NTJ>
__device__ __forceinline__ void gemm_tile(const bf16_t* A, const bf16_t* B,
                                          int mb, int nb, int l16, int q,
                                          f32x4 (&acc)[2][NTJ]) {
#pragma unroll
  for (int kt = 0; kt < KI; ++kt) {
    const int sw = ((kt * 4 + q) ^ l16) << 3;
    bf16x8 a0 = *(const bf16x8*)(A + ((mb + l16) << 7) + sw);
    bf16x8 a1 = *(const bf16x8*)(A + ((mb + 16 + l16) << 7) + sw);
#pragma unroll
    for (int tj = 0; tj < NTJ; ++tj) {
      bf16x8 b = *(const bf16x8*)(B + ((nb + tj * 16 + l16) << 7) + sw);
      acc[0][tj] = __builtin_amdgcn_mfma_f32_16x16x32_bf16(a0, b, acc[0][tj], 0, 0, 0);
      acc[1][tj] = __builtin_amdgcn_mfma_f32_16x16x32_bf16(a1, b, acc[1][tj], 0, 0, 0);
    }
  }
}

// Load transposed bf16 weight [N][K] global -> perm'd+swizzled LDS.
template<int ROWS, int K8>
__device__ __forceinline__ void load_wT(bf16_t* dst, const bf16_t* src, int tid) {
  const uint4* s = (const uint4*)src;
#pragma unroll
  for (int i = tid; i < ROWS * K8; i += 256) {
    const int n = i / K8, k8 = i % K8;
    const int row = permrow(n);
    *(uint4*)(dst + (row << 7) + ((k8 ^ (row & 15)) << 3)) = s[i];
  }
}

// Stage fp32 [rows][K] tile -> swizzled bf16 LDS. C4 = K/4.
template<int C4>
__device__ __forceinline__ void stage_x(bf16_t* dst, const float* src, int tid) {
  const float4* g = (const float4*)src;
#pragma unroll
  for (int i = tid; i < 64 * C4; i += 256) {
    const int row = i / C4, c4 = i % C4;
    float4 v = g[i];
    bf16_t t[4] = {(bf16_t)v.x, (bf16_t)v.y, (bf16_t)v.z, (bf16_t)v.w};
    *(uint2*)(dst + (row << 7) + ((((c4 >> 1) ^ (row & 15)) << 3) | ((c4 & 1) << 2))) =
        *(const uint2*)t;
  }
}

// =====================  K0: weight preprocessing  =====================
// Transpose all fp32 weights to bf16 [N][K]; fuse W_rbf1@W_rbf2 -> wcb[b][n][8].
__global__ void prep_kernel(
    const float* __restrict__ W_ji, const float* __restrict__ W_kj,
    const float* __restrict__ W_down, const float* __restrict__ W_up,
    const float* __restrict__ rb1, const float* __restrict__ rb2,
    const float* __restrict__ W_lin, const float* __restrict__ ra1,
    const float* __restrict__ ra2, const float* __restrict__ W_rbf1,
    const float* __restrict__ W_rbf2,
    bf16_t* __restrict__ wjiT, bf16_t* __restrict__ wkjT,
    bf16_t* __restrict__ wdownT, bf16_t* __restrict__ wupT,
    bf16_t* __restrict__ rb1T, bf16_t* __restrict__ rb2T,
    bf16_t* __restrict__ linT, bf16_t* __restrict__ ra1T,
    bf16_t* __restrict__ ra2T, bf16_t* __restrict__ wcb)
{
  const int tid = threadIdx.x;
  if (blockIdx.x >= 112) {
    const int o = (blockIdx.x - 112) * 256 + tid;
    if (o < 640) {
      const int b = o >> 7, n = o & 127;
      bf16_t t[8];
#pragma unroll
      for (int r = 0; r < 6; ++r) {
        const float* w1 = W_rbf1 + (b + 1) * 48 + r * 8;
        const float* w2 = W_rbf2 + (b + 1) * 1024 + n;
        float s = 0.f;
#pragma unroll
        for (int c = 0; c < 8; ++c) s += w1[c] * w2[c * 128];
        t[r] = (bf16_t)s;
      }
      t[6] = (bf16_t)0.f; t[7] = (bf16_t)0.f;
      *(uint4*)(wcb + (b * 128 + n) * 8) = *(const uint4*)t;
    }
    return;
  }
  const int c = blockIdx.x * 256 + tid;
  const float* src; bf16_t* dst; int n, k8, N, K;
  if (c < 22528) {
    const int m = c >> 11, w = c & 2047;
    n = w >> 4; k8 = w & 15; N = 128; K = 128;
    if (m == 0)      { src = W_ji;  dst = wjiT; }
    else if (m <= 5) { src = W_kj + m * 16384; dst = wkjT + (m - 1) * 16384; }
    else if (m == 6) { src = rb1;   dst = rb1T; }
    else if (m == 7) { src = rb2;   dst = rb2T; }
    else if (m == 8) { src = W_lin; dst = linT; }
    else if (m == 9) { src = ra1;   dst = ra1T; }
    else             { src = ra2;   dst = ra2T; }
  } else if (c < 27648) {
    const int m = (c - 22528) >> 10, w = (c - 22528) & 1023;
    n = w >> 4; k8 = w & 15; N = 64; K = 128;
    src = W_down + (m + 1) * 8192; dst = wdownT + m * 8192;
  } else {
    const int w = c - 27648;
    n = w >> 3; k8 = w & 7; N = 128; K = 64;
    src = W_up; dst = wupT;
  }
  bf16_t t[8];
#pragma unroll
  for (int j = 0; j < 8; ++j) t[j] = (bf16_t)src[(k8 * 8 + j) * N + n];
  *(uint4*)(dst + n * K + k8 * 8) = *(const uint4*)t;
}

// =====================  K1: edge-level GEMMs (branch-parallel)  =====================
// LDS cut to 66 KB (tmpA aliases rbfA/WcB) -> 2 blocks/CU instead of 1.
__global__ __launch_bounds__(256, 2)
void edge_kernel(const float* __restrict__ x, const float* __restrict__ rbf,
                 const float* __restrict__ b_kj, const float* __restrict__ b_ji,
                 const bf16_t* __restrict__ wjiT, const bf16_t* __restrict__ wkjT,
                 const bf16_t* __restrict__ wdownT, const bf16_t* __restrict__ wcb,
                 bf16_t* __restrict__ x_ji_out, bf16_t* __restrict__ down)
{
  __shared__ bf16_t xA[64 * 128];     // x tile; reused for Wdown B-tile
  __shared__ bf16_t Wb[128 * 128];
  __shared__ bf16_t tmpA[64 * 128];   // also holds rbfA (64*40) + WcB (128*40)
  __shared__ float biasS[128];
  bf16_t* const rbfA = tmpA;          // zero-padded K=32 A-tile for rbf GEMM
  bf16_t* const WcB  = tmpA + 64 * 40; // zero-padded B-tile (perm'd rows)

  const int tid = threadIdx.x;
  const int lane = tid & 63, wv = tid >> 6;
  const int q = lane >> 4, l16 = lane & 15;
  const int mb = (wv >> 1) * 32, nb = (wv & 1) * 64;
  const int R = blockIdx.x * 64;
  const int br = blockIdx.y;   // 0 = x_ji, 1..5 = branch pipelines

  stage_x<32>(xA, x + (size_t)R * 128, tid);
  if (br == 0) {
    load_wT<128, 16>(Wb, wjiT, tid);
    if (tid < 128) biasS[tid] = b_ji[tid];
  } else {
    load_wT<128, 16>(Wb, wkjT + (br - 1) * 16384, tid);
    if (tid < 128) biasS[tid] = b_kj[br * 128 + tid];
    const uint4 z = {0, 0, 0, 0};
    if (tid < 64) {
      const float* rg = rbf + (size_t)(R + tid) * 6;
      bf16_t t[8] = {(bf16_t)rg[0], (bf16_t)rg[1], (bf16_t)rg[2],
                     (bf16_t)rg[3], (bf16_t)rg[4], (bf16_t)rg[5],
                     (bf16_t)0.f, (bf16_t)0.f};
      *(uint4*)(rbfA + tid * 40)      = *(const uint4*)t;
      *(uint4*)(rbfA + tid * 40 + 8)  = z;
      *(uint4*)(rbfA + tid * 40 + 16) = z;
      *(uint4*)(rbfA + tid * 40 + 24) = z;
    } else if (tid >= 128) {
      const int n = tid - 128;   // 0..127, perm'd row order
      const int row = permrow(n);
      uint4 w = ((const uint4*)(wcb + (size_t)(br - 1) * 1024))[n];
      *(uint4*)(WcB + row * 40)      = w;
      *(uint4*)(WcB + row * 40 + 8)  = z;
      *(uint4*)(WcB + row * 40 + 16) = z;
      *(uint4*)(WcB + row * 40 + 24) = z;
    }
  }
  __syncthreads();

  f32x4 acc[2][4] = {};
  gemm_tile<4, 4>(xA, Wb, mb, nb, l16, q, acc);

  if (br == 0) {
#pragma unroll
    for (int ti = 0; ti < 2; ++ti)
#pragma unroll
      for (int r = 0; r < 4; ++r) {
        const int row = mb + ti * 16 + q * 4 + r;
#pragma unroll
        for (int gl = 0; gl < 2; ++gl) {
          const int col0 = nb + gl * 32 + 2 * l16;
          const float2 b2 = *(const float2*)&biasS[col0];
          *(uint32_t*)&x_ji_out[(size_t)(R + row) * 128 + col0] =
              pack_bf16(silu_f(acc[ti][2 * gl][r] + b2.x),
                        silu_f(acc[ti][2 * gl + 1][r] + b2.y));
        }
      }
    return;
  }

  // rbf_p = rbf @ Wc via one-K-step MFMA (real K=6, padded to 32)
  f32x4 accr[2][4] = {};
  {
    bf16x8 a0 = *(const bf16x8*)(rbfA + (mb + l16) * 40 + q * 8);
    bf16x8 a1 = *(const bf16x8*)(rbfA + (mb + 16 + l16) * 40 + q * 8);
#pragma unroll
    for (int tj = 0; tj < 4; ++tj) {
      bf16x8 b = *(const bf16x8*)(WcB + (nb + tj * 16 + l16) * 40 + q * 8);
      accr[0][tj] = __builtin_amdgcn_mfma_f32_16x16x32_bf16(a0, b, accr[0][tj], 0, 0, 0);
      accr[1][tj] = __builtin_amdgcn_mfma_f32_16x16x32_bf16(a1, b, accr[1][tj], 0, 0, 0);
    }
  }
  __syncthreads();   // all reads of rbfA/WcB done before tmpA overwrites them

  // tmp = silu(x@Wkj + b) * rbf_p  -> swizzled A-layout in tmpA
#pragma unroll
  for (int ti = 0; ti < 2; ++ti)
#pragma unroll
    for (int r = 0; r < 4; ++r) {
      const int row = mb + ti * 16 + q * 4 + r;
#pragma unroll
      for (int gl = 0; gl < 2; ++gl) {
        const int col0 = nb + gl * 32 + 2 * l16;
        const float2 b2 = *(const float2*)&biasS[col0];
        const float v0 = silu_f(acc[ti][2 * gl][r] + b2.x) * accr[ti][2 * gl][r];
        const float v1 = silu_f(acc[ti][2 * gl + 1][r] + b2.y) * accr[ti][2 * gl + 1][r];
        *(uint32_t*)&tmpA[(row << 7) + ((((col0 >> 3) ^ (row & 15)) << 3) | (col0 & 7))] =
            pack_bf16(v0, v1);
      }
    }
  __syncthreads();
  load_wT<64, 16>(xA, wdownT + (br - 1) * 8192, tid);   // Wdown into xA space
  __syncthreads();

  const int nb2 = (wv & 1) * 32;
  f32x4 acc2[2][2] = {};
  gemm_tile<4, 2>(tmpA, xA, mb, nb2, l16, q, acc2);
#pragma unroll
  for (int ti = 0; ti < 2; ++ti)
#pragma unroll
    for (int r = 0; r < 4; ++r) {
      const int row = mb + ti * 16 + q * 4 + r;
      const int col0 = nb2 + 2 * l16;
      *(uint32_t*)&down[((size_t)(br - 1) * E_N + R + row) * 64 + col0] =
          pack_bf16(silu_f(acc2[ti][0][r]), silu_f(acc2[ti][1][r]));
    }
}

// =====================  K2: triplet c8 projection + CSR bucket build  =====================
// c8g[t][0..7]  = sbf[t] @ W1[5]   (alpha / branch-5 part)
// c8g[t][8..15] = sbf[t] @ W1[bs]  (band-type part), bs = bt[kj]+1
// meta[t] = kj | bs<<16 ; bucket insert t into list[ji][*] (overflow -> ovf list)
__global__ __launch_bounds__(256, 4)
void c8_kernel(const float* __restrict__ sbf, const int* __restrict__ idx_kj,
               const int* __restrict__ idx_ji, const int* __restrict__ bt,
               const float* __restrict__ Wsbf1,
               float* __restrict__ c8g, uint32_t* __restrict__ meta,
               int* __restrict__ cnt, int* __restrict__ list,
               int* __restrict__ ovf)   // ovf[0]=count, pairs (t,ji) from ovf[2]
{
  __shared__ float s_sbf[64 * 44];
  __shared__ float s_W1[2016];   // [6][42][8]
  __shared__ float s_c8[64 * 16];
  __shared__ int s_bs[64];

  const int tid = threadIdx.x;
  const int base = blockIdx.x * 64;

  for (int i = tid; i < 2016; i += 256) s_W1[i] = Wsbf1[i];
  if (tid < 64) {
    const int t = base + tid;
    const int kj = idx_kj[t];
    const int ji = idx_ji[t];
    const int bs = bt[kj] + 1;   // BT_LIST[b] = b-1 for b>=1; bt in [0,5)
    s_bs[tid] = bs;
    meta[t] = (uint32_t)kj | ((uint32_t)bs << 16);
    const int pos = atomicAdd(&cnt[ji], 1);
    if (pos < CAP) {
      list[ji * CAP + pos] = t;
    } else {
      const int o = atomicAdd(&ovf[0], 1);
      if (o < OVF_MAX) { ovf[2 + 2 * o] = t; ovf[2 + 2 * o + 1] = ji; }
    }
  }
  {
    const float2* sg = (const float2*)(sbf + (size_t)base * 42);
    for (int i = tid; i < 64 * 21; i += 256) {
      const int r = i / 21, c2 = i - r * 21;
      const float2 v = sg[i];
      s_sbf[r * 44 + c2 * 2] = v.x;
      s_sbf[r * 44 + c2 * 2 + 1] = v.y;
    }
  }
  __syncthreads();

  { // c8[i][brr*8+c] : brr=0 -> branch 5, brr=1 -> branch bs
    const int i = tid >> 2;
    const int brr = (tid >> 1) & 1;
    const int cg = tid & 1;
    const int b = brr ? s_bs[i] : 5;
    const float* w = &s_W1[b * 336 + cg * 4];
    const float* sb = &s_sbf[i * 44];
    float a0 = 0.f, a1 = 0.f, a2 = 0.f, a3 = 0.f;
#pragma unroll
    for (int s = 0; s < 42; ++s) {
      const float sv = sb[s];
      const float* ws = w + s * 8;
      a0 += sv * ws[0]; a1 += sv * ws[1]; a2 += sv * ws[2]; a3 += sv * ws[3];
    }
    float* dc = &s_c8[i * 16 + brr * 8 + cg * 4];
    dc[0] = a0; dc[1] = a1; dc[2] = a2; dc[3] = a3;
  }
  __syncthreads();

  { // coalesced write-out: 256 threads x float4 = 64 triplets x 16 floats
    const float4* s4 = (const float4*)s_c8;
    float4* g4 = (float4*)(c8g + (size_t)base * 16);
    g4[tid] = s4[tid];
  }
}

// =====================  K3: per-edge gather (replaces atomic scatter)  =====================
// One wave per edge (lane = j). Walks the edge's triplet bucket, accumulates in
// registers, writes xkj once, coalesced. No float atomics, no memset of xkj.
__global__ __launch_bounds__(256, 8)
void gather_kernel(const int* __restrict__ cnt, const int* __restrict__ list,
                   const uint32_t* __restrict__ meta, const float* __restrict__ c8g,
                   const float* __restrict__ Wsbf2, const bf16_t* __restrict__ down,
                   const float* __restrict__ alpha_p, const int* __restrict__ ovf,
                   float* __restrict__ xkj)
{
  __shared__ float sW2[3072];   // [6][8][64]
  for (int i = threadIdx.x; i < 3072; i += 256) sW2[i] = Wsbf2[i];
  __syncthreads();

  const int e = blockIdx.x * 4 + (threadIdx.x >> 6);
  const int j = threadIdx.x & 63;
  const float alpha = alpha_p[0], oma = 1.f - alpha;
  const float* w5 = &sW2[5 * 512 + j];

  float acc = 0.f;
  int n = cnt[e];
  if (n > CAP) n = CAP;
#pragma unroll 2
  for (int k = 0; k < n; ++k) {
    const int t = __builtin_amdgcn_readfirstlane(list[e * CAP + k]);
    const uint32_t m = __builtin_amdgcn_readfirstlane(meta[t]);
    const int kj = m & 0xffff;
    const int b  = m >> 16;
    const float g5 = (float)down[((size_t)4 * E_N + kj) * 64 + j];
    const float gb = (float)down[((size_t)(b - 1) * E_N + kj) * 64 + j];
    const float* cp = c8g + (size_t)t * 16;
    float d5 = 0.f, db = 0.f;
#pragma unroll
    for (int c = 0; c < 8; ++c) {
      d5 += cp[c]     * w5[c * 64];
      db += cp[8 + c] * sW2[b * 512 + c * 64 + j];
    }
    acc += alpha * g5 * d5 + oma * gb * db;
  }

  const int oc = ovf[0];       // normally 0; full correctness fallback
  for (int k = 0; k < oc; ++k) {
    const int ji = ovf[2 + 2 * k + 1];
    if (ji != e) continue;
    const int t = ovf[2 + 2 * k];
    const uint32_t m = meta[t];
    const int kj = m & 0xffff;
    const int b  = m >> 16;
    const float g5 = (float)down[((size_t)4 * E_N + kj) * 64 + j];
    const float gb = (float)down[((size_t)(b - 1) * E_N + kj) * 64 + j];
    const float* cp = c8g + (size_t)t * 16;
    float d5 = 0.f, db = 0.f;
#pragma unroll
    for (int c = 0; c < 8; ++c) {
      d5 += cp[c]     * w5[c * 64];
      db += cp[8 + c] * sW2[b * 512 + c * 64 + j];
    }
    acc += alpha * g5 * d5 + oma * gb * db;
  }

  xkj[(size_t)e * 64 + j] = acc;
}

// =====================  K4: fused epilogue chain  =====================
__global__ __launch_bounds__(256, 2)
void epi_kernel(const float* __restrict__ x, const bf16_t* __restrict__ x_ji,
                const float* __restrict__ xkj,
                const bf16_t* __restrict__ wupT,
                const bf16_t* __restrict__ rb1T, const float* __restrict__ rb1_b,
                const bf16_t* __restrict__ rb2T, const float* __restrict__ rb2_b,
                const bf16_t* __restrict__ linT, const float* __restrict__ lin_b,
                const bf16_t* __restrict__ ra1T, const float* __restrict__ ra1_b,
                const bf16_t* __restrict__ ra2T, const float* __restrict__ ra2_b,
                float* __restrict__ out)
{
  __shared__ bf16_t bufA[64 * 128];
  __shared__ bf16_t bufB[64 * 128];
  __shared__ bf16_t Wb[128 * 128];
  __shared__ float biasS[128];

  const int tid = threadIdx.x;
  const int lane = tid & 63, wv = tid >> 6;
  const int q = lane >> 4, l16 = lane & 15;
  const int mb = (wv >> 1) * 32, nb = (wv & 1) * 64;
  const int R = blockIdx.x * 64;

  stage_x<16>(bufA, xkj + (size_t)R * 64, tid);
  load_wT<128, 8>(Wb, wupT, tid);
  __syncthreads();

  f32x4 hreg[2][4];
  { // h = x_ji + silu(xkj @ W_up)  -> bufB
    f32x4 acc[2][4] = {};
    gemm_tile<2, 4>(bufA, Wb, mb, nb, l16, q, acc);
#pragma unroll
    for (int ti = 0; ti < 2; ++ti)
#pragma unroll
      for (int r = 0; r < 4; ++r) {
        const int row = mb + ti * 16 + q * 4 + r;
#pragma unroll
        for (int gl = 0; gl < 2; ++gl) {
          const int col0 = nb + gl * 32 + 2 * l16;
          union { uint32_t u; bf16x2 h; } xj;
          xj.u = *(const uint32_t*)&x_ji[(size_t)(R + row) * 128 + col0];
          const float h0 = (float)xj.h[0] + silu_f(acc[ti][2 * gl][r]);
          const float h1 = (float)xj.h[1] + silu_f(acc[ti][2 * gl + 1][r]);
          hreg[ti][2 * gl][r] = h0;
          hreg[ti][2 * gl + 1][r] = h1;
          *(uint32_t*)&bufB[(row << 7) + ((((col0 >> 3) ^ (row & 15)) << 3) | (col0 & 7))] =
              pack_bf16(h0, h1);
        }
      }
  }

#define EPI_STAGE(ASRC, WSRC, BIAS, BODY)                                        \
  __syncthreads();                                                               \
  load_wT<128, 16>(Wb, WSRC, tid);                                               \
  if (tid < 128) biasS[tid] = BIAS[tid];                                         \
  __syncthreads();                                                               \
  {                                                                              \
    f32x4 acc[2][4] = {};                                                        \
    gemm_tile<4, 4>(ASRC, Wb, mb, nb, l16, q, acc);                              \
    _Pragma("unroll")                                                            \
    for (int ti = 0; ti < 2; ++ti)                                               \
      _Pragma("unroll")                                                          \
      for (int r = 0; r < 4; ++r) {                                              \
        const int row = mb + ti * 16 + q * 4 + r;                                \
        _Pragma("unroll")                                                        \
        for (int gl = 0; gl < 2; ++gl) {                                         \
          const int col0 = nb + gl * 32 + 2 * l16;                               \
          const float2 b2 = *(const float2*)&biasS[col0];                        \
          const float g0 = acc[ti][2 * gl][r] + b2.x;                            \
          const float g1 = acc[ti][2 * gl + 1][r] + b2.y;                        \
          BODY                                                                   \
        }                                                                        \
      }                                                                          \
  }

  // stage 1: u = silu(h @ rb1 + b) -> bufA
  EPI_STAGE(bufB, rb1T, rb1_b, {
    *(uint32_t*)&bufA[(row << 7) + ((((col0 >> 3) ^ (row & 15)) << 3) | (col0 & 7))] =
        pack_bf16(silu_f(g0), silu_f(g1));
  })

  // stage 2: h += silu(u @ rb2 + b) -> bufB
  EPI_STAGE(bufA, rb2T, rb2_b, {
    const float h0 = hreg[ti][2 * gl][r] + silu_f(g0);
    const float h1 = hreg[ti][2 * gl + 1][r] + silu_f(g1);
    hreg[ti][2 * gl][r] = h0; hreg[ti][2 * gl + 1][r] = h1;
    *(uint32_t*)&bufB[(row << 7) + ((((col0 >> 3) ^ (row & 15)) << 3) | (col0 & 7))] =
        pack_bf16(h0, h1);
  })

  // stage 3: h = silu(h @ W_lin + b) + x -> bufA
  EPI_STAGE(bufB, linT, lin_b, {
    const float2 xv = *(const float2*)&x[(size_t)(R + row) * 128 + col0];
    const float h0 = silu_f(g0) + xv.x;
    const float h1 = silu_f(g1) + xv.y;
    hreg[ti][2 * gl][r] = h0; hreg[ti][2 * gl + 1][r] = h1;
    *(uint32_t*)&bufA[(row << 7) + ((((col0 >> 3) ^ (row & 15)) << 3) | (col0 & 7))] =
        pack_bf16(h0, h1);
  })

  // stage 4: u = silu(h @ ra1 + b) -> bufB
  EPI_STAGE(bufA, ra1T, ra1_b, {
    *(uint32_t*)&bufB[(row << 7) + ((((col0 >> 3) ^ (row & 15)) << 3) | (col0 & 7))] =
        pack_bf16(silu_f(g0), silu_f(g1));
  })

  // stage 5: out = h + silu(u @ ra2 + b)
  EPI_STAGE(bufB, ra2T, ra2_b, {
    float2 o;
    o.x = hreg[ti][2 * gl][r] + silu_f(g0);
    o.y = hreg[ti][2 * gl + 1][r] + silu_f(g1);
    *(float2*)&out[(size_t)(R + row) * 128 + col0] = o;
  })
#undef EPI_STAGE
}

extern "C" void kernel_launch(void* const* d_in, const int* in_sizes, int n_in,
                              void* d_out, int out_size, void* d_ws, size_t ws_size,
                              hipStream_t stream)
{
  (void)in_sizes; (void)n_in; (void)out_size; (void)ws_size;
  const float* x      = (const float*)d_in[0];
  const float* rbf    = (const float*)d_in[1];
  const float* sbf    = (const float*)d_in[2];
  const int*   idx_kj = (const int*)d_in[3];
  const int*   idx_ji = (const int*)d_in[4];
  const int*   bt     = (const int*)d_in[5];
  const float* alpha  = (const float*)d_in[7];
  const float* W_kj   = (const float*)d_in[8];
  const float* b_kj   = (const float*)d_in[9];
  const float* W_rbf1 = (const float*)d_in[10];
  const float* W_rbf2 = (const float*)d_in[11];
  const float* W_sbf1 = (const float*)d_in[12];
  const float* W_sbf2 = (const float*)d_in[13];
  const float* W_down = (const float*)d_in[14];
  const float* W_ji   = (const float*)d_in[15];
  const float* b_ji   = (const float*)d_in[16];
  const float* W_up   = (const float*)d_in[17];
  const float* rb1_w  = (const float*)d_in[18];
  const float* rb1_b  = (const float*)d_in[19];
  const float* rb2_w  = (const float*)d_in[20];
  const float* rb2_b  = (const float*)d_in[21];
  const float* W_lin  = (const float*)d_in[22];
  const float* b_lin  = (const float*)d_in[23];
  const float* ra1_w  = (const float*)d_in[24];
  const float* ra1_b  = (const float*)d_in[25];
  const float* ra2_w  = (const float*)d_in[26];
  const float* ra2_b  = (const float*)d_in[27];

  char* ws = (char*)d_ws;
  bf16_t* down   = (bf16_t*)(ws);                 // 5*E*64*2  = 41,943,040
  bf16_t* x_ji   = (bf16_t*)(ws + 41943040);      // E*128*2   = 16,777,216
  float*  xkj    = (float*) (ws + 58720256);      // E*64*4    = 16,777,216
  char* wbase    = ws + 75497472;
  bf16_t* wjiT   = (bf16_t*)(wbase + 0);
  bf16_t* wkjT   = (bf16_t*)(wbase + 32768);
  bf16_t* wdownT = (bf16_t*)(wbase + 196608);
  bf16_t* wupT   = (bf16_t*)(wbase + 278528);
  bf16_t* rb1T   = (bf16_t*)(wbase + 294912);
  bf16_t* rb2T   = (bf16_t*)(wbase + 327680);
  bf16_t* linT   = (bf16_t*)(wbase + 360448);
  bf16_t* ra1T   = (bf16_t*)(wbase + 393216);
  bf16_t* ra2T   = (bf16_t*)(wbase + 425984);
  bf16_t* wcb    = (bf16_t*)(wbase + 458752);     // 5*128*8*2 = 10,240
  float*    c8g  = (float*)   (ws + 75966464);    // T*16*4    = 16,777,216
  uint32_t* meta = (uint32_t*)(ws + 92743680);    // T*4       =  1,048,576
  int*      list = (int*)     (ws + 93792256);    // E*CAP*4   =  4,194,304
  int*      cnt  = (int*)     (ws + 97986560);    // E*4       =    262,144
  int*      ovf  = (int*)     (ws + 98248704);    // 8 + 2*T*4 =  2,097,160

  hipMemsetAsync(cnt, 0, 262144 + 8, stream);     // cnt + ovf[0..1]
  prep_kernel<<<115, 256, 0, stream>>>(W_ji, W_kj, W_down, W_up, rb1_w, rb2_w,
                                       W_lin, ra1_w, ra2_w, W_rbf1, W_rbf2,
                                       wjiT, wkjT, wdownT, wupT, rb1T, rb2T,
                                       linT, ra1T, ra2T, wcb);
  edge_kernel<<<dim3(E_N / 64, 6), 256, 0, stream>>>(x, rbf, b_kj, b_ji, wjiT,
                                                     wkjT, wdownT, wcb, x_ji, down);
  c8_kernel<<<T_N / 64, 256, 0, stream>>>(sbf, idx_kj, idx_ji, bt, W_sbf1,
                                          c8g, meta, cnt, list, ovf);
  gather_kernel<<<E_N / 4 / 64, 256, 0, stream>>>(cnt, list, meta, c8g, W_sbf2,
                                                  down, alpha, ovf, xkj);
  epi_kernel<<<E_N / 64, 256, 0, stream>>>(x, x_ji, xkj, wupT, rb1T, rb1_b,
                                           rb2T, rb2_b, linT, b_lin,
                                           ra1T, ra1_b, ra2T, ra2_b,
                                           (float*)d_out);
}